// Round 11
// baseline (458.460 us; speedup 1.0000x reference)
//
#include <hip/hip_runtime.h>
#include <hip/hip_bf16.h>

#define N_NODES 50000
#define N_EDGES 800000
#define DIN 128
#define DH   256
#define DOUT 128
#define EPSV 1e-5f
#define SLOPE 0.01f
#define SCAN_NB ((N_NODES + 255) / 256)   // 196

typedef __bf16 bf16x8 __attribute__((ext_vector_type(8)));
typedef __bf16 bf16x4 __attribute__((ext_vector_type(4)));
typedef float  f32x4  __attribute__((ext_vector_type(4)));

// ---------------- merged weight cast f32 -> bf16 ----------------
__global__ void cast3_kernel(const float* __restrict__ W0, const float* __restrict__ W1,
                             const float* __restrict__ W2,
                             __bf16* __restrict__ w0b, __bf16* __restrict__ w1b,
                             __bf16* __restrict__ w2b) {
    constexpr int n0 = DH * DIN / 4, n1 = DH * DH / 4, n2 = DOUT * DH / 4;
    int i = blockIdx.x * blockDim.x + threadIdx.x;
    const float* src; __bf16* dst; int k;
    if (i < n0)           { src = W0; dst = w0b; k = i; }
    else if (i < n0 + n1) { src = W1; dst = w1b; k = i - n0; }
    else if (i < n0 + n1 + n2) { src = W2; dst = w2b; k = i - n0 - n1; }
    else return;
    float4 v = ((const float4*)src)[k];
    bf16x4 o; o[0] = (__bf16)v.x; o[1] = (__bf16)v.y; o[2] = (__bf16)v.z; o[3] = (__bf16)v.w;
    ((bf16x4*)dst)[k] = o;
}

// ---- cast + row-scale by dinv: xb[r] = dinv[r] * x[r], row-major bf16 ----
__global__ void cast_scale_kernel(const float* __restrict__ src, const float* __restrict__ dinv,
                                  __bf16* __restrict__ dst) {
    int i = blockIdx.x * blockDim.x + threadIdx.x;   // one bf16x8 unit
    if (i < N_NODES * (DIN / 8)) {
        int row = i / (DIN / 8);
        float d = dinv[row];
        float4 a = ((const float4*)src)[i * 2];
        float4 b = ((const float4*)src)[i * 2 + 1];
        bf16x8 o;
        o[0] = (__bf16)(a.x * d); o[1] = (__bf16)(a.y * d);
        o[2] = (__bf16)(a.z * d); o[3] = (__bf16)(a.w * d);
        o[4] = (__bf16)(b.x * d); o[5] = (__bf16)(b.y * d);
        o[6] = (__bf16)(b.z * d); o[7] = (__bf16)(b.w * d);
        ((bf16x8*)dst)[i] = o;
    }
}

// ---------------- CSR build ----------------
__global__ void deg_kernel(const int* __restrict__ dst, int* __restrict__ deg) {
    int i = blockIdx.x * blockDim.x + threadIdx.x;
    if (i < N_EDGES) atomicAdd(&deg[dst[i]], 1);
}

// per-block sums of (deg+1); also emits dinv (fused)
__global__ __launch_bounds__(256) void scan_bsum(const int* __restrict__ deg,
                                                 int* __restrict__ bsum,
                                                 float* __restrict__ dinv) {
    __shared__ int lds[256];
    int i = blockIdx.x * 256 + threadIdx.x;
    int dv = 0;
    if (i < N_NODES) {
        dv = deg[i] + 1;
        dinv[i] = rsqrtf((float)dv);
    }
    lds[threadIdx.x] = dv;
    __syncthreads();
    #pragma unroll
    for (int off = 128; off > 0; off >>= 1) {
        if (threadIdx.x < off) lds[threadIdx.x] += lds[threadIdx.x + off];
        __syncthreads();
    }
    if (threadIdx.x == 0) bsum[blockIdx.x] = lds[0];
}

__global__ __launch_bounds__(256) void scan_boffs(const int* __restrict__ bsum,
                                                  int* __restrict__ boffs) {
    __shared__ int lds[256];
    const int t = threadIdx.x;
    lds[t] = (t < SCAN_NB) ? bsum[t] : 0;
    __syncthreads();
    #pragma unroll
    for (int off = 1; off < 256; off <<= 1) {
        int add = (t >= off) ? lds[t - off] : 0;
        __syncthreads();
        lds[t] += add;
        __syncthreads();
    }
    boffs[t] = (t == 0) ? 0 : lds[t - 1];   // exclusive
}

__global__ __launch_bounds__(256) void scan_write(const int* __restrict__ deg,
                                                  const int* __restrict__ boffs,
                                                  int* __restrict__ rp) {
    __shared__ int lds[256];
    const int t = threadIdx.x;
    int i = blockIdx.x * 256 + t;
    int v = (i < N_NODES) ? deg[i] + 1 : 0;
    lds[t] = v;
    __syncthreads();
    #pragma unroll
    for (int off = 1; off < 256; off <<= 1) {
        int add = (t >= off) ? lds[t - off] : 0;
        __syncthreads();
        lds[t] += add;
        __syncthreads();
    }
    if (i < N_NODES) rp[i] = boffs[blockIdx.x] + lds[t] - v;
    if (i == N_NODES - 1) rp[N_NODES] = boffs[blockIdx.x] + lds[t];
}

// weightless CSR: one 4B NT store per edge; self-loop takes the reserved last slot
__global__ void scatter_kernel(const int* __restrict__ ei,
                               const int* __restrict__ rp, int* __restrict__ cursor,
                               int* __restrict__ csr) {
    int e = blockIdx.x * blockDim.x + threadIdx.x;
    if (e >= N_EDGES + N_NODES) return;
    int pos, src;
    if (e < N_EDGES) {
        src = ei[e]; int dst = ei[N_EDGES + e];
        pos = rp[dst] + atomicAdd(&cursor[dst], 1);
    } else {
        src = e - N_EDGES;
        pos = rp[src + 1] - 1;             // reserved slot, no atomic
    }
    __builtin_nontemporal_store(src, &csr[pos]);
}

// ---------------- SpMM: out[r] = dinv[r] * sum_e h[src[e]]  (h pre-scaled by dinv) ----
// row-major h; C8 = C/8 bf16x8 lanes per row
template<int C8>
__global__ __launch_bounds__(256) void spmm_b(const int* __restrict__ rp,
                                              const int* __restrict__ csr,
                                              const float* __restrict__ dinv,
                                              const __bf16* __restrict__ h,
                                              __bf16* __restrict__ outp) {
    constexpr int RPB = 256 / C8;
    const int r = blockIdx.x * RPB + threadIdx.x / C8;
    const int l = threadIdx.x % C8;
    if (r >= N_NODES) return;
    const bf16x8* __restrict__ h8 = (const bf16x8*)h;
    const int e0 = rp[r], e1 = rp[r + 1];
    float acc0[8] = {}, acc1[8] = {};
    int e = e0;
    for (; e + 8 <= e1; e += 8) {
        int p[8];
        #pragma unroll
        for (int u = 0; u < 8; ++u) p[u] = __builtin_nontemporal_load(csr + e + u);
        bf16x8 v[8];
        #pragma unroll
        for (int u = 0; u < 8; ++u) v[u] = h8[(long)p[u] * C8 + l];
        #pragma unroll
        for (int u = 0; u < 8; ++u) {
            #pragma unroll
            for (int j = 0; j < 8; ++j) {
                if (u & 1) acc1[j] += (float)v[u][j];
                else       acc0[j] += (float)v[u][j];
            }
        }
    }
    for (; e + 2 <= e1; e += 2) {
        int p0 = __builtin_nontemporal_load(csr + e);
        int p1 = __builtin_nontemporal_load(csr + e + 1);
        bf16x8 v0 = h8[(long)p0 * C8 + l];
        bf16x8 v1 = h8[(long)p1 * C8 + l];
        #pragma unroll
        for (int j = 0; j < 8; ++j) {
            acc0[j] += (float)v0[j];
            acc1[j] += (float)v1[j];
        }
    }
    if (e < e1) {
        int p0 = __builtin_nontemporal_load(csr + e);
        bf16x8 v0 = h8[(long)p0 * C8 + l];
        #pragma unroll
        for (int j = 0; j < 8; ++j) acc0[j] += (float)v0[j];
    }
    const float d = dinv[r];
    bf16x8 ob;
    #pragma unroll
    for (int j = 0; j < 8; ++j) ob[j] = (__bf16)((acc0[j] + acc1[j]) * d);
    ((bf16x8*)outp)[(long)r * C8 + l] = ob;
}

// ---------------- bf16 MFMA GEMM, double-buffered LDS, 1 barrier / K-step ----------------
// C = act(BN(A)) @ W^T ; optional dinv row-scale; optional fused BN-stats partials
template<int K, int NC, bool FUSE_BN, bool RELU, bool SCALE, bool FUSE_STATS>
__global__ __launch_bounds__(256) void gemm_tile(const __bf16* __restrict__ A,
                                                 const __bf16* __restrict__ W,
                                                 const float* __restrict__ ss,
                                                 const float* __restrict__ dinv,
                                                 __bf16* __restrict__ C,
                                                 float* __restrict__ partial,
                                                 int M) {
    constexpr int NW = NC / 64;
    constexpr int MW = 4 / NW;
    constexpr int BM = MW * 64;
    constexpr int NSTEP = K / 32;
    __shared__ __bf16 As[2][BM][40];

    const int tid = threadIdx.x;
    const int wave = tid >> 6, lane = tid & 63;
    const int ln15 = lane & 15, kg = lane >> 4;
    const int wm = wave / NW, wn = wave % NW;
    const int m0 = blockIdx.x * BM;
    const int srow = tid >> 2, schunk = tid & 3;

    int grow[MW];
    #pragma unroll
    for (int p = 0; p < MW; ++p) {
        int gr = m0 + p * 64 + srow;
        grow[p] = gr < M ? gr : M - 1;
    }

    f32x4 acc[4][4];
    #pragma unroll
    for (int i = 0; i < 4; ++i)
        #pragma unroll
        for (int j = 0; j < 4; ++j) acc[i][j] = (f32x4){0.f, 0.f, 0.f, 0.f};

#define LOAD_A(vv, kt_)                                                         \
    _Pragma("unroll")                                                           \
    for (int p = 0; p < MW; ++p)                                                \
        vv[p] = *(const bf16x8*)(A + (long)grow[p] * K + (kt_) + schunk * 8);

#define XFORM_A(vv, kt_)                                                        \
    if (FUSE_BN) {                                                              \
        const f32x4* ss4 = (const f32x4*)ss;                                    \
        int ci = ((kt_) + schunk * 8) >> 2;                                     \
        f32x4 sc0 = ss4[ci],            sc1 = ss4[ci + 1];                      \
        f32x4 sh0 = ss4[(K >> 2) + ci], sh1 = ss4[(K >> 2) + ci + 1];           \
        _Pragma("unroll")                                                       \
        for (int p = 0; p < MW; ++p) {                                          \
            float f[8];                                                         \
            _Pragma("unroll")                                                   \
            for (int j = 0; j < 4; ++j) {                                       \
                f[j]     = fmaf((float)vv[p][j],     sc0[j], sh0[j]);           \
                f[j + 4] = fmaf((float)vv[p][j + 4], sc1[j], sh1[j]);           \
            }                                                                   \
            if (RELU) {                                                         \
                _Pragma("unroll")                                               \
                for (int j = 0; j < 8; ++j) f[j] = f[j] > 0.f ? f[j] : SLOPE * f[j]; \
            }                                                                   \
            _Pragma("unroll")                                                   \
            for (int j = 0; j < 8; ++j) vv[p][j] = (__bf16)f[j];                \
        }                                                                       \
    }

#define WRITE_A(buf, vv)                                                        \
    _Pragma("unroll")                                                           \
    for (int p = 0; p < MW; ++p)                                                \
        *(bf16x8*)(&As[buf][p * 64 + srow][schunk * 8]) = vv[p];

    bf16x8 v0[MW], v[MW];
    LOAD_A(v0, 0)
    XFORM_A(v0, 0)
    WRITE_A(0, v0)
    if (NSTEP > 1) {
        LOAD_A(v, 32)
        XFORM_A(v, 32)
    }
    __syncthreads();

    int cur = 0;
    #pragma unroll
    for (int step = 0; step < NSTEP; ++step) {
        const int kt = step * 32;
        if (step + 1 < NSTEP) {
            WRITE_A(cur ^ 1, v)
        }
        bf16x8 vn[MW];
        if (step + 2 < NSTEP) {
            LOAD_A(vn, kt + 64)
        }
        bf16x8 b[4];
        #pragma unroll
        for (int j = 0; j < 4; ++j)
            b[j] = *(const bf16x8*)(W + (long)(wn * 64 + j * 16 + ln15) * K + kt + kg * 8);
        #pragma unroll
        for (int i = 0; i < 4; ++i) {
            bf16x8 a = *(const bf16x8*)(&As[cur][wm * 64 + i * 16 + ln15][kg * 8]);
            #pragma unroll
            for (int j = 0; j < 4; ++j)
                acc[i][j] = __builtin_amdgcn_mfma_f32_16x16x32_bf16(a, b[j], acc[i][j], 0, 0, 0);
        }
        if (step + 2 < NSTEP) {
            XFORM_A(vn, kt + 64)
            #pragma unroll
            for (int p = 0; p < MW; ++p) v[p] = vn[p];
        }
        __syncthreads();
        cur ^= 1;
    }
#undef LOAD_A
#undef XFORM_A
#undef WRITE_A

    // epilogue: store bf16 (optional dinv scale); optional per-block BN-stats partials
    float sst[4] = {}, qst[4] = {};
    #pragma unroll
    for (int i = 0; i < 4; ++i) {
        #pragma unroll
        for (int q = 0; q < 4; ++q) {
            int r = m0 + wm * 64 + i * 16 + kg * 4 + q;
            bool ok = r < M;
            int rc = ok ? r : 0;
            float d = SCALE ? dinv[rc] : 1.0f;
            #pragma unroll
            for (int j = 0; j < 4; ++j) {
                __bf16 bv = (__bf16)(acc[i][j][q] * d);
                if (ok) {
                    C[(long)r * NC + wn * 64 + j * 16 + ln15] = bv;
                    if (FUSE_STATS) {
                        float fv = (float)bv;
                        sst[j] += fv; qst[j] += fv * fv;
                    }
                }
            }
        }
    }
    if (FUSE_STATS) {
        #pragma unroll
        for (int j = 0; j < 4; ++j) {
            sst[j] += __shfl_xor(sst[j], 16, 64);
            sst[j] += __shfl_xor(sst[j], 32, 64);
            qst[j] += __shfl_xor(qst[j], 16, 64);
            qst[j] += __shfl_xor(qst[j], 32, 64);
        }
        if (kg == 0) {
            #pragma unroll
            for (int j = 0; j < 4; ++j) {
                int col = wn * 64 + j * 16 + ln15;
                partial[(long)blockIdx.x * (2 * NC) + col]      = sst[j];
                partial[(long)blockIdx.x * (2 * NC) + NC + col] = qst[j];
            }
        }
    }
}

// ---------------- BN stats: per-block partial sums (atomic-free, bf16 input) ----------
#define NB_STATS 128
template<int C>
__global__ __launch_bounds__(256) void bn_stats(const __bf16* __restrict__ hp,
                                                float* __restrict__ partial) {
    constexpr int LPR = C / 4;
    constexpr int RPI = 256 / LPR;
    const int chunk = threadIdx.x % LPR;
    const int rof   = threadIdx.x / LPR;
    float s[4] = {}, s2[4] = {};
    for (int r = blockIdx.x * RPI + rof; r < N_NODES; r += NB_STATS * RPI) {
        bf16x4 x = ((const bf16x4*)hp)[(long)r * LPR + chunk];
        #pragma unroll
        for (int j = 0; j < 4; ++j) {
            float v = (float)x[j];
            s[j] += v; s2[j] += v * v;
        }
    }
    __shared__ float red[256 * 8];
    #pragma unroll
    for (int j = 0; j < 4; ++j) { red[threadIdx.x * 8 + j] = s[j]; red[threadIdx.x * 8 + 4 + j] = s2[j]; }
    __syncthreads();
    if (rof == 0) {
        #pragma unroll
        for (int g = 1; g < RPI; ++g) {
            #pragma unroll
            for (int j = 0; j < 4; ++j) {
                s[j]  += red[(g * LPR + chunk) * 8 + j];
                s2[j] += red[(g * LPR + chunk) * 8 + 4 + j];
            }
        }
        #pragma unroll
        for (int j = 0; j < 4; ++j) {
            partial[blockIdx.x * 2 * C + chunk * 4 + j]     = s[j];
            partial[blockIdx.x * 2 * C + C + chunk * 4 + j] = s2[j];
        }
    }
}

// ---------------- reduce nb partial blocks -> per-column scale/shift ----------------
template<int C>
__global__ void bn_reduce(const float* __restrict__ partial, int nb,
                          const float* __restrict__ g, const float* __restrict__ be,
                          float* __restrict__ ss) {
    int c = threadIdx.x;
    float s = 0.f, q = 0.f;
    #pragma unroll 4
    for (int b = 0; b < nb; ++b) {
        s += partial[(long)b * 2 * C + c];
        q += partial[(long)b * 2 * C + C + c];
    }
    const float invn = 1.0f / (float)N_NODES;
    float mean = s * invn;
    float var  = q * invn - mean * mean;
    float rstd = rsqrtf(var + EPSV);
    float sc = g[c] * rstd;
    ss[c] = sc;
    ss[C + c] = be[c] - mean * sc;
}

// ---------------- final BN apply: bf16 in -> f32 out ----------------
template<int C>
__global__ __launch_bounds__(256) void bn_apply_b2f(const __bf16* __restrict__ in,
                                                    float* __restrict__ outp,
                                                    const float* __restrict__ ss) {
    constexpr int LPR = C / 4;
    const long total = (long)N_NODES * LPR;
    const long stride = (long)gridDim.x * blockDim.x;
    for (long idx = (long)blockIdx.x * blockDim.x + threadIdx.x; idx < total; idx += stride) {
        int chunk = (int)(idx % LPR);
        float4 sc = ((const float4*)ss)[chunk];
        float4 sh = ((const float4*)(ss + C))[chunk];
        bf16x4 x = ((const bf16x4*)in)[idx];
        float4 o;
        o.x = fmaf((float)x[0], sc.x, sh.x);
        o.y = fmaf((float)x[1], sc.y, sh.y);
        o.z = fmaf((float)x[2], sc.z, sh.z);
        o.w = fmaf((float)x[3], sc.w, sh.w);
        ((float4*)outp)[idx] = o;
    }
}

extern "C" void kernel_launch(void* const* d_in, const int* in_sizes, int n_in,
                              void* d_out, int out_size, void* d_ws, size_t ws_size,
                              hipStream_t stream) {
    const float* x   = (const float*)d_in[0];
    const int*   ei  = (const int*)  d_in[1];
    const float* W0  = (const float*)d_in[2];
    const float* g0  = (const float*)d_in[4];
    const float* be0 = (const float*)d_in[5];
    const float* W1  = (const float*)d_in[6];
    const float* g1  = (const float*)d_in[8];
    const float* be1 = (const float*)d_in[9];
    const float* W2  = (const float*)d_in[10];
    const float* g2  = (const float*)d_in[12];
    const float* be2 = (const float*)d_in[13];
    float* out = (float*)d_out;

    const int GEMM0_NB = (N_NODES + 63) / 64;   // 782

    char* wsb = (char*)d_ws;
    auto alloc = [&](size_t bytes) { char* p = wsb; wsb += (bytes + 255) & ~255UL; return p; };
    int*    deg     = (int*)   alloc(N_NODES * 4);       // deg + cursor adjacent: one memset
    int*    cursor  = (int*)   alloc(N_NODES * 4);
    int*    rp      = (int*)   alloc((N_NODES + 4) * 4);
    float*  dinv    = (float*) alloc(N_NODES * 4);
    int*    bsum    = (int*)   alloc(256 * 4);
    int*    boffs   = (int*)   alloc(257 * 4);
    float*  partial = (float*) alloc((size_t)GEMM0_NB * 2 * DH * 4);  // covers all stats users
    float*  ss      = (float*) alloc(2 * DH * 4);
    int*    csr     = (int*)   alloc((size_t)(N_EDGES + N_NODES) * 4);
    __bf16* w0b     = (__bf16*)alloc(DH * DIN * 2);
    __bf16* w1b     = (__bf16*)alloc(DH * DH * 2);
    __bf16* w2b     = (__bf16*)alloc(DOUT * DH * 2);
    __bf16* xb      = (__bf16*)alloc((size_t)N_NODES * DIN * 2);
    __bf16* bf0     = (__bf16*)alloc((size_t)N_NODES * DH * 2);
    __bf16* bf1     = (__bf16*)alloc((size_t)N_NODES * DH * 2);

    // ---- single memset covering deg .. cursor ----
    hipMemsetAsync(deg, 0, (size_t)((char*)cursor - (char*)deg) + N_NODES * 4, stream);

    // ---- merged weight casts ----
    cast3_kernel<<<(DH * DIN / 4 + DH * DH / 4 + DOUT * DH / 4 + 255) / 256, 256, 0, stream>>>(
        W0, W1, W2, w0b, w1b, w2b);

    // ---- CSR build (dinv fused into scan_bsum) ----
    deg_kernel<<<(N_EDGES + 255) / 256, 256, 0, stream>>>(ei + N_EDGES, deg);
    scan_bsum<<<SCAN_NB, 256, 0, stream>>>(deg, bsum, dinv);
    scan_boffs<<<1, 256, 0, stream>>>(bsum, boffs);
    scan_write<<<SCAN_NB, 256, 0, stream>>>(deg, boffs, rp);
    scatter_kernel<<<(N_EDGES + N_NODES + 255) / 256, 256, 0, stream>>>(ei, rp, cursor, csr);

    // ---- x -> bf16 pre-scaled by dinv ----
    cast_scale_kernel<<<(N_NODES * (DIN / 8) + 255) / 256, 256, 0, stream>>>(x, dinv, xb);

    // ---- layer 0: aggregate xb (C=128) -> gemm0 (fused stats) -> reduce ----
    spmm_b<DIN / 8><<<(N_NODES * (DIN / 8) + 255) / 256, 256, 0, stream>>>(
        rp, csr, dinv, xb, bf0);
    gemm_tile<DIN, DH, false, false, false, true><<<GEMM0_NB, 256, 0, stream>>>(
        bf0, w0b, nullptr, nullptr, bf1, partial, N_NODES);
    bn_reduce<DH><<<1, DH, 0, stream>>>(partial, GEMM0_NB, g0, be0, ss);

    // ---- layer 1: gemm (fused BN0+leaky, dinv-scaled) -> aggregate -> stats ----
    gemm_tile<DH, DH, true, true, true, false><<<(N_NODES + 63) / 64, 256, 0, stream>>>(
        bf1, w1b, ss, dinv, bf0, nullptr, N_NODES);
    spmm_b<DH / 8><<<(N_NODES * (DH / 8) + 255) / 256, 256, 0, stream>>>(
        rp, csr, dinv, bf0, bf1);
    bn_stats<DH><<<NB_STATS, 256, 0, stream>>>(bf1, partial);
    bn_reduce<DH><<<1, DH, 0, stream>>>(partial, NB_STATS, g1, be1, ss);

    // ---- layer 2: gemm (fused BN1+leaky, dinv-scaled) -> aggregate bf16 -> stats -> BN ----
    gemm_tile<DH, DOUT, true, true, true, false><<<(N_NODES + 127) / 128, 256, 0, stream>>>(
        bf1, w2b, ss, dinv, bf0, nullptr, N_NODES);
    spmm_b<DOUT / 8><<<(N_NODES * (DOUT / 8) + 255) / 256, 256, 0, stream>>>(
        rp, csr, dinv, bf0, bf1);
    bn_stats<DOUT><<<NB_STATS, 256, 0, stream>>>(bf1, partial);
    bn_reduce<DOUT><<<1, DOUT, 0, stream>>>(partial, NB_STATS, g2, be2, ss);
    bn_apply_b2f<DOUT><<<2048, 256, 0, stream>>>(bf1, out, ss);
}

// Round 12
// 407.185 us; speedup vs baseline: 1.1259x; 1.1259x over previous
//
#include <hip/hip_runtime.h>
#include <hip/hip_bf16.h>

#define N_NODES 50000
#define N_EDGES 800000
#define DIN 128
#define DH   256
#define DOUT 128
#define EPSV 1e-5f
#define SLOPE 0.01f
#define SCAN_NB ((N_NODES + 255) / 256)   // 196

typedef __bf16 bf16x8 __attribute__((ext_vector_type(8)));
typedef __bf16 bf16x4 __attribute__((ext_vector_type(4)));
typedef float  f32x4  __attribute__((ext_vector_type(4)));

// ---------------- merged weight cast f32 -> bf16 ----------------
__global__ void cast3_kernel(const float* __restrict__ W0, const float* __restrict__ W1,
                             const float* __restrict__ W2,
                             __bf16* __restrict__ w0b, __bf16* __restrict__ w1b,
                             __bf16* __restrict__ w2b) {
    constexpr int n0 = DH * DIN / 4, n1 = DH * DH / 4, n2 = DOUT * DH / 4;
    int i = blockIdx.x * blockDim.x + threadIdx.x;
    const float* src; __bf16* dst; int k;
    if (i < n0)           { src = W0; dst = w0b; k = i; }
    else if (i < n0 + n1) { src = W1; dst = w1b; k = i - n0; }
    else if (i < n0 + n1 + n2) { src = W2; dst = w2b; k = i - n0 - n1; }
    else return;
    float4 v = ((const float4*)src)[k];
    bf16x4 o; o[0] = (__bf16)v.x; o[1] = (__bf16)v.y; o[2] = (__bf16)v.z; o[3] = (__bf16)v.w;
    ((bf16x4*)dst)[k] = o;
}

// ---- cast + row-scale by dinv: xb[r] = dinv[r] * x[r], row-major bf16 ----
__global__ void cast_scale_kernel(const float* __restrict__ src, const float* __restrict__ dinv,
                                  __bf16* __restrict__ dst) {
    int i = blockIdx.x * blockDim.x + threadIdx.x;   // one bf16x8 unit
    if (i < N_NODES * (DIN / 8)) {
        int row = i / (DIN / 8);
        float d = dinv[row];
        float4 a = ((const float4*)src)[i * 2];
        float4 b = ((const float4*)src)[i * 2 + 1];
        bf16x8 o;
        o[0] = (__bf16)(a.x * d); o[1] = (__bf16)(a.y * d);
        o[2] = (__bf16)(a.z * d); o[3] = (__bf16)(a.w * d);
        o[4] = (__bf16)(b.x * d); o[5] = (__bf16)(b.y * d);
        o[6] = (__bf16)(b.z * d); o[7] = (__bf16)(b.w * d);
        ((bf16x8*)dst)[i] = o;
    }
}

// ---------------- CSR build ----------------
__global__ void deg_kernel(const int* __restrict__ dst, int* __restrict__ deg) {
    int i = blockIdx.x * blockDim.x + threadIdx.x;
    if (i < N_EDGES) atomicAdd(&deg[dst[i]], 1);
}

// per-block sums of (deg+1); also emits dinv (fused)
__global__ __launch_bounds__(256) void scan_bsum(const int* __restrict__ deg,
                                                 int* __restrict__ bsum,
                                                 float* __restrict__ dinv) {
    __shared__ int lds[256];
    int i = blockIdx.x * 256 + threadIdx.x;
    int dv = 0;
    if (i < N_NODES) {
        dv = deg[i] + 1;
        dinv[i] = rsqrtf((float)dv);
    }
    lds[threadIdx.x] = dv;
    __syncthreads();
    #pragma unroll
    for (int off = 128; off > 0; off >>= 1) {
        if (threadIdx.x < off) lds[threadIdx.x] += lds[threadIdx.x + off];
        __syncthreads();
    }
    if (threadIdx.x == 0) bsum[blockIdx.x] = lds[0];
}

__global__ __launch_bounds__(256) void scan_boffs(const int* __restrict__ bsum,
                                                  int* __restrict__ boffs) {
    __shared__ int lds[256];
    const int t = threadIdx.x;
    lds[t] = (t < SCAN_NB) ? bsum[t] : 0;
    __syncthreads();
    #pragma unroll
    for (int off = 1; off < 256; off <<= 1) {
        int add = (t >= off) ? lds[t - off] : 0;
        __syncthreads();
        lds[t] += add;
        __syncthreads();
    }
    boffs[t] = (t == 0) ? 0 : lds[t - 1];   // exclusive
}

__global__ __launch_bounds__(256) void scan_write(const int* __restrict__ deg,
                                                  const int* __restrict__ boffs,
                                                  int* __restrict__ rp) {
    __shared__ int lds[256];
    const int t = threadIdx.x;
    int i = blockIdx.x * 256 + t;
    int v = (i < N_NODES) ? deg[i] + 1 : 0;
    lds[t] = v;
    __syncthreads();
    #pragma unroll
    for (int off = 1; off < 256; off <<= 1) {
        int add = (t >= off) ? lds[t - off] : 0;
        __syncthreads();
        lds[t] += add;
        __syncthreads();
    }
    if (i < N_NODES) rp[i] = boffs[blockIdx.x] + lds[t] - v;
    if (i == N_NODES - 1) rp[N_NODES] = boffs[blockIdx.x] + lds[t];
}

// weightless CSR: one plain 4B store per edge; self-loop takes the reserved last slot
__global__ void scatter_kernel(const int* __restrict__ ei,
                               const int* __restrict__ rp, int* __restrict__ cursor,
                               int* __restrict__ csr) {
    int e = blockIdx.x * blockDim.x + threadIdx.x;
    if (e >= N_EDGES + N_NODES) return;
    int pos, src;
    if (e < N_EDGES) {
        src = ei[e]; int dst = ei[N_EDGES + e];
        pos = rp[dst] + atomicAdd(&cursor[dst], 1);
    } else {
        src = e - N_EDGES;
        pos = rp[src + 1] - 1;             // reserved slot, no atomic
    }
    csr[pos] = src;
}

// ---------------- SpMM: out[r] = dinv[r] * sum_e h[src[e]]  (h pre-scaled by dinv) ----
// row-major h; C8 = C/8 bf16x8 lanes per row; plain loads (R8-proven)
template<int C8>
__global__ __launch_bounds__(256) void spmm_b(const int* __restrict__ rp,
                                              const int* __restrict__ csr,
                                              const float* __restrict__ dinv,
                                              const __bf16* __restrict__ h,
                                              __bf16* __restrict__ outp) {
    constexpr int RPB = 256 / C8;
    const int r = blockIdx.x * RPB + threadIdx.x / C8;
    const int l = threadIdx.x % C8;
    if (r >= N_NODES) return;
    const bf16x8* __restrict__ h8 = (const bf16x8*)h;
    const int e0 = rp[r], e1 = rp[r + 1];
    float acc0[8] = {}, acc1[8] = {};
    int e = e0;
    for (; e + 8 <= e1; e += 8) {
        int p[8];
        #pragma unroll
        for (int u = 0; u < 8; ++u) p[u] = csr[e + u];
        bf16x8 v[8];
        #pragma unroll
        for (int u = 0; u < 8; ++u) v[u] = h8[(long)p[u] * C8 + l];
        #pragma unroll
        for (int u = 0; u < 8; ++u) {
            #pragma unroll
            for (int j = 0; j < 8; ++j) {
                if (u & 1) acc1[j] += (float)v[u][j];
                else       acc0[j] += (float)v[u][j];
            }
        }
    }
    for (; e + 2 <= e1; e += 2) {
        int p0 = csr[e], p1 = csr[e + 1];
        bf16x8 v0 = h8[(long)p0 * C8 + l];
        bf16x8 v1 = h8[(long)p1 * C8 + l];
        #pragma unroll
        for (int j = 0; j < 8; ++j) {
            acc0[j] += (float)v0[j];
            acc1[j] += (float)v1[j];
        }
    }
    if (e < e1) {
        int p0 = csr[e];
        bf16x8 v0 = h8[(long)p0 * C8 + l];
        #pragma unroll
        for (int j = 0; j < 8; ++j) acc0[j] += (float)v0[j];
    }
    const float d = dinv[r];
    bf16x8 ob;
    #pragma unroll
    for (int j = 0; j < 8; ++j) ob[j] = (__bf16)((acc0[j] + acc1[j]) * d);
    ((bf16x8*)outp)[(long)r * C8 + l] = ob;
}

// ---------------- bf16 MFMA GEMM, double-buffered LDS, 1 barrier / K-step ----------------
// C = act(BN(A)) @ W^T ; optional dinv row-scale
template<int K, int NC, bool FUSE_BN, bool RELU, bool SCALE>
__global__ __launch_bounds__(256) void gemm_tile(const __bf16* __restrict__ A,
                                                 const __bf16* __restrict__ W,
                                                 const float* __restrict__ ss,
                                                 const float* __restrict__ dinv,
                                                 __bf16* __restrict__ C,
                                                 int M) {
    constexpr int NW = NC / 64;
    constexpr int MW = 4 / NW;
    constexpr int BM = MW * 64;
    constexpr int NSTEP = K / 32;
    __shared__ __bf16 As[2][BM][40];

    const int tid = threadIdx.x;
    const int wave = tid >> 6, lane = tid & 63;
    const int ln15 = lane & 15, kg = lane >> 4;
    const int wm = wave / NW, wn = wave % NW;
    const int m0 = blockIdx.x * BM;
    const int srow = tid >> 2, schunk = tid & 3;

    int grow[MW];
    #pragma unroll
    for (int p = 0; p < MW; ++p) {
        int gr = m0 + p * 64 + srow;
        grow[p] = gr < M ? gr : M - 1;
    }

    f32x4 acc[4][4];
    #pragma unroll
    for (int i = 0; i < 4; ++i)
        #pragma unroll
        for (int j = 0; j < 4; ++j) acc[i][j] = (f32x4){0.f, 0.f, 0.f, 0.f};

#define LOAD_A(vv, kt_)                                                         \
    _Pragma("unroll")                                                           \
    for (int p = 0; p < MW; ++p)                                                \
        vv[p] = *(const bf16x8*)(A + (long)grow[p] * K + (kt_) + schunk * 8);

#define XFORM_A(vv, kt_)                                                        \
    if (FUSE_BN) {                                                              \
        const f32x4* ss4 = (const f32x4*)ss;                                    \
        int ci = ((kt_) + schunk * 8) >> 2;                                     \
        f32x4 sc0 = ss4[ci],            sc1 = ss4[ci + 1];                      \
        f32x4 sh0 = ss4[(K >> 2) + ci], sh1 = ss4[(K >> 2) + ci + 1];           \
        _Pragma("unroll")                                                       \
        for (int p = 0; p < MW; ++p) {                                          \
            float f[8];                                                         \
            _Pragma("unroll")                                                   \
            for (int j = 0; j < 4; ++j) {                                       \
                f[j]     = fmaf((float)vv[p][j],     sc0[j], sh0[j]);           \
                f[j + 4] = fmaf((float)vv[p][j + 4], sc1[j], sh1[j]);           \
            }                                                                   \
            if (RELU) {                                                         \
                _Pragma("unroll")                                               \
                for (int j = 0; j < 8; ++j) f[j] = f[j] > 0.f ? f[j] : SLOPE * f[j]; \
            }                                                                   \
            _Pragma("unroll")                                                   \
            for (int j = 0; j < 8; ++j) vv[p][j] = (__bf16)f[j];                \
        }                                                                       \
    }

#define WRITE_A(buf, vv)                                                        \
    _Pragma("unroll")                                                           \
    for (int p = 0; p < MW; ++p)                                                \
        *(bf16x8*)(&As[buf][p * 64 + srow][schunk * 8]) = vv[p];

    bf16x8 v0[MW], v[MW];
    LOAD_A(v0, 0)
    XFORM_A(v0, 0)
    WRITE_A(0, v0)
    if (NSTEP > 1) {
        LOAD_A(v, 32)
        XFORM_A(v, 32)
    }
    __syncthreads();

    int cur = 0;
    #pragma unroll
    for (int step = 0; step < NSTEP; ++step) {
        const int kt = step * 32;
        if (step + 1 < NSTEP) {
            WRITE_A(cur ^ 1, v)
        }
        bf16x8 vn[MW];
        if (step + 2 < NSTEP) {
            LOAD_A(vn, kt + 64)
        }
        bf16x8 b[4];
        #pragma unroll
        for (int j = 0; j < 4; ++j)
            b[j] = *(const bf16x8*)(W + (long)(wn * 64 + j * 16 + ln15) * K + kt + kg * 8);
        #pragma unroll
        for (int i = 0; i < 4; ++i) {
            bf16x8 a = *(const bf16x8*)(&As[cur][wm * 64 + i * 16 + ln15][kg * 8]);
            #pragma unroll
            for (int j = 0; j < 4; ++j)
                acc[i][j] = __builtin_amdgcn_mfma_f32_16x16x32_bf16(a, b[j], acc[i][j], 0, 0, 0);
        }
        if (step + 2 < NSTEP) {
            XFORM_A(vn, kt + 64)
            #pragma unroll
            for (int p = 0; p < MW; ++p) v[p] = vn[p];
        }
        __syncthreads();
        cur ^= 1;
    }
#undef LOAD_A
#undef XFORM_A
#undef WRITE_A

    #pragma unroll
    for (int i = 0; i < 4; ++i) {
        #pragma unroll
        for (int q = 0; q < 4; ++q) {
            int r = m0 + wm * 64 + i * 16 + kg * 4 + q;
            if (r < M) {
                float d = SCALE ? dinv[r] : 1.0f;
                #pragma unroll
                for (int j = 0; j < 4; ++j)
                    C[(long)r * NC + wn * 64 + j * 16 + ln15] = (__bf16)(acc[i][j][q] * d);
            }
        }
    }
}

// ---------------- BN stats: per-block partial sums (atomic-free, bf16 input) ----------
#define NB_STATS 128
template<int C>
__global__ __launch_bounds__(256) void bn_stats(const __bf16* __restrict__ hp,
                                                float* __restrict__ partial) {
    constexpr int LPR = C / 4;
    constexpr int RPI = 256 / LPR;
    const int chunk = threadIdx.x % LPR;
    const int rof   = threadIdx.x / LPR;
    float s[4] = {}, s2[4] = {};
    for (int r = blockIdx.x * RPI + rof; r < N_NODES; r += NB_STATS * RPI) {
        bf16x4 x = ((const bf16x4*)hp)[(long)r * LPR + chunk];
        #pragma unroll
        for (int j = 0; j < 4; ++j) {
            float v = (float)x[j];
            s[j] += v; s2[j] += v * v;
        }
    }
    __shared__ float red[256 * 8];
    #pragma unroll
    for (int j = 0; j < 4; ++j) { red[threadIdx.x * 8 + j] = s[j]; red[threadIdx.x * 8 + 4 + j] = s2[j]; }
    __syncthreads();
    if (rof == 0) {
        #pragma unroll
        for (int g = 1; g < RPI; ++g) {
            #pragma unroll
            for (int j = 0; j < 4; ++j) {
                s[j]  += red[(g * LPR + chunk) * 8 + j];
                s2[j] += red[(g * LPR + chunk) * 8 + 4 + j];
            }
        }
        #pragma unroll
        for (int j = 0; j < 4; ++j) {
            partial[blockIdx.x * 2 * C + chunk * 4 + j]     = s[j];
            partial[blockIdx.x * 2 * C + C + chunk * 4 + j] = s2[j];
        }
    }
}

// ---------------- reduce partials -> scale/shift (1024 threads, parallel groups) ----
template<int C>
__global__ __launch_bounds__(1024) void bn_reduce(const float* __restrict__ partial, int nb,
                                                  const float* __restrict__ g,
                                                  const float* __restrict__ be,
                                                  float* __restrict__ ss) {
    constexpr int G = 1024 / C;          // 4 (C=256) or 8 (C=128) parallel groups
    const int c = threadIdx.x % C;
    const int grp = threadIdx.x / C;
    float s = 0.f, q = 0.f;
    for (int b = grp; b < nb; b += G) {
        s += partial[(long)b * 2 * C + c];
        q += partial[(long)b * 2 * C + C + c];
    }
    __shared__ float reds[1024], redq[1024];
    reds[threadIdx.x] = s; redq[threadIdx.x] = q;
    __syncthreads();
    if (grp == 0) {
        #pragma unroll
        for (int gg = 1; gg < G; ++gg) { s += reds[gg * C + c]; q += redq[gg * C + c]; }
        const float invn = 1.0f / (float)N_NODES;
        float mean = s * invn;
        float var  = q * invn - mean * mean;
        float rstd = rsqrtf(var + EPSV);
        float sc = g[c] * rstd;
        ss[c] = sc;
        ss[C + c] = be[c] - mean * sc;
    }
}

// ---------------- final BN apply: bf16 in -> f32 out ----------------
template<int C>
__global__ __launch_bounds__(256) void bn_apply_b2f(const __bf16* __restrict__ in,
                                                    float* __restrict__ outp,
                                                    const float* __restrict__ ss) {
    constexpr int LPR = C / 4;
    const long total = (long)N_NODES * LPR;
    const long stride = (long)gridDim.x * blockDim.x;
    for (long idx = (long)blockIdx.x * blockDim.x + threadIdx.x; idx < total; idx += stride) {
        int chunk = (int)(idx % LPR);
        float4 sc = ((const float4*)ss)[chunk];
        float4 sh = ((const float4*)(ss + C))[chunk];
        bf16x4 x = ((const bf16x4*)in)[idx];
        float4 o;
        o.x = fmaf((float)x[0], sc.x, sh.x);
        o.y = fmaf((float)x[1], sc.y, sh.y);
        o.z = fmaf((float)x[2], sc.z, sh.z);
        o.w = fmaf((float)x[3], sc.w, sh.w);
        ((float4*)outp)[idx] = o;
    }
}

extern "C" void kernel_launch(void* const* d_in, const int* in_sizes, int n_in,
                              void* d_out, int out_size, void* d_ws, size_t ws_size,
                              hipStream_t stream) {
    const float* x   = (const float*)d_in[0];
    const int*   ei  = (const int*)  d_in[1];
    const float* W0  = (const float*)d_in[2];
    const float* g0  = (const float*)d_in[4];
    const float* be0 = (const float*)d_in[5];
    const float* W1  = (const float*)d_in[6];
    const float* g1  = (const float*)d_in[8];
    const float* be1 = (const float*)d_in[9];
    const float* W2  = (const float*)d_in[10];
    const float* g2  = (const float*)d_in[12];
    const float* be2 = (const float*)d_in[13];
    float* out = (float*)d_out;

    char* wsb = (char*)d_ws;
    auto alloc = [&](size_t bytes) { char* p = wsb; wsb += (bytes + 255) & ~255UL; return p; };
    int*    deg     = (int*)   alloc(N_NODES * 4);       // deg + cursor adjacent: one memset
    int*    cursor  = (int*)   alloc(N_NODES * 4);
    int*    rp      = (int*)   alloc((N_NODES + 4) * 4);
    float*  dinv    = (float*) alloc(N_NODES * 4);
    int*    bsum    = (int*)   alloc(256 * 4);
    int*    boffs   = (int*)   alloc(257 * 4);
    float*  partial = (float*) alloc(NB_STATS * 2 * DH * 4);
    float*  ss      = (float*) alloc(2 * DH * 4);
    int*    csr     = (int*)   alloc((size_t)(N_EDGES + N_NODES) * 4);
    __bf16* w0b     = (__bf16*)alloc(DH * DIN * 2);
    __bf16* w1b     = (__bf16*)alloc(DH * DH * 2);
    __bf16* w2b     = (__bf16*)alloc(DOUT * DH * 2);
    __bf16* xb      = (__bf16*)alloc((size_t)N_NODES * DIN * 2);
    __bf16* bf0     = (__bf16*)alloc((size_t)N_NODES * DH * 2);
    __bf16* bf1     = (__bf16*)alloc((size_t)N_NODES * DH * 2);

    // ---- single memset covering deg .. cursor ----
    hipMemsetAsync(deg, 0, (size_t)((char*)cursor - (char*)deg) + N_NODES * 4, stream);

    // ---- merged weight casts ----
    cast3_kernel<<<(DH * DIN / 4 + DH * DH / 4 + DOUT * DH / 4 + 255) / 256, 256, 0, stream>>>(
        W0, W1, W2, w0b, w1b, w2b);

    // ---- CSR build (dinv fused into scan_bsum) ----
    deg_kernel<<<(N_EDGES + 255) / 256, 256, 0, stream>>>(ei + N_EDGES, deg);
    scan_bsum<<<SCAN_NB, 256, 0, stream>>>(deg, bsum, dinv);
    scan_boffs<<<1, 256, 0, stream>>>(bsum, boffs);
    scan_write<<<SCAN_NB, 256, 0, stream>>>(deg, boffs, rp);
    scatter_kernel<<<(N_EDGES + N_NODES + 255) / 256, 256, 0, stream>>>(ei, rp, cursor, csr);

    // ---- x -> bf16 pre-scaled by dinv ----
    cast_scale_kernel<<<(N_NODES * (DIN / 8) + 255) / 256, 256, 0, stream>>>(x, dinv, xb);

    // ---- layer 0: aggregate xb (C=128) -> gemm0 -> stats ----
    spmm_b<DIN / 8><<<(N_NODES * (DIN / 8) + 255) / 256, 256, 0, stream>>>(
        rp, csr, dinv, xb, bf0);
    gemm_tile<DIN, DH, false, false, false><<<(N_NODES + 63) / 64, 256, 0, stream>>>(
        bf0, w0b, nullptr, nullptr, bf1, N_NODES);
    bn_stats<DH><<<NB_STATS, 256, 0, stream>>>(bf1, partial);
    bn_reduce<DH><<<1, 1024, 0, stream>>>(partial, NB_STATS, g0, be0, ss);

    // ---- layer 1: gemm (fused BN0+leaky, dinv-scaled) -> aggregate -> stats ----
    gemm_tile<DH, DH, true, true, true><<<(N_NODES + 63) / 64, 256, 0, stream>>>(
        bf1, w1b, ss, dinv, bf0, N_NODES);
    spmm_b<DH / 8><<<(N_NODES * (DH / 8) + 255) / 256, 256, 0, stream>>>(
        rp, csr, dinv, bf0, bf1);
    bn_stats<DH><<<NB_STATS, 256, 0, stream>>>(bf1, partial);
    bn_reduce<DH><<<1, 1024, 0, stream>>>(partial, NB_STATS, g1, be1, ss);

    // ---- layer 2: gemm (fused BN1+leaky, dinv-scaled) -> aggregate bf16 -> stats -> BN ----
    gemm_tile<DH, DOUT, true, true, true><<<(N_NODES + 127) / 128, 256, 0, stream>>>(
        bf1, w2b, ss, dinv, bf0, N_NODES);
    spmm_b<DOUT / 8><<<(N_NODES * (DOUT / 8) + 255) / 256, 256, 0, stream>>>(
        rp, csr, dinv, bf0, bf1);
    bn_stats<DOUT><<<NB_STATS, 256, 0, stream>>>(bf1, partial);
    bn_reduce<DOUT><<<1, 1024, 0, stream>>>(partial, NB_STATS, g2, be2, ss);
    bn_apply_b2f<DOUT><<<2048, 256, 0, stream>>>(bf1, out, ss);
}

// Round 13
// 406.990 us; speedup vs baseline: 1.1265x; 1.0005x over previous
//
#include <hip/hip_runtime.h>
#include <hip/hip_bf16.h>

#define N_NODES 50000
#define N_EDGES 800000
#define DIN 128
#define DH   256
#define DOUT 128
#define EPSV 1e-5f
#define SLOPE 0.01f
#define SCAN_NB ((N_NODES + 255) / 256)   // 196
#define NBUCKET ((N_NODES + 63) / 64)     // 782

typedef __bf16 bf16x8 __attribute__((ext_vector_type(8)));
typedef __bf16 bf16x4 __attribute__((ext_vector_type(4)));
typedef float  f32x4  __attribute__((ext_vector_type(4)));

// ---------------- merged weight cast f32 -> bf16 ----------------
__global__ void cast3_kernel(const float* __restrict__ W0, const float* __restrict__ W1,
                             const float* __restrict__ W2,
                             __bf16* __restrict__ w0b, __bf16* __restrict__ w1b,
                             __bf16* __restrict__ w2b) {
    constexpr int n0 = DH * DIN / 4, n1 = DH * DH / 4, n2 = DOUT * DH / 4;
    int i = blockIdx.x * blockDim.x + threadIdx.x;
    const float* src; __bf16* dst; int k;
    if (i < n0)           { src = W0; dst = w0b; k = i; }
    else if (i < n0 + n1) { src = W1; dst = w1b; k = i - n0; }
    else if (i < n0 + n1 + n2) { src = W2; dst = w2b; k = i - n0 - n1; }
    else return;
    float4 v = ((const float4*)src)[k];
    bf16x4 o; o[0] = (__bf16)v.x; o[1] = (__bf16)v.y; o[2] = (__bf16)v.z; o[3] = (__bf16)v.w;
    ((bf16x4*)dst)[k] = o;
}

// ---- cast + row-scale by dinv: xb[r] = dinv[r] * x[r], row-major bf16 ----
__global__ void cast_scale_kernel(const float* __restrict__ src, const float* __restrict__ dinv,
                                  __bf16* __restrict__ dst) {
    int i = blockIdx.x * blockDim.x + threadIdx.x;   // one bf16x8 unit
    if (i < N_NODES * (DIN / 8)) {
        int row = i / (DIN / 8);
        float d = dinv[row];
        float4 a = ((const float4*)src)[i * 2];
        float4 b = ((const float4*)src)[i * 2 + 1];
        bf16x8 o;
        o[0] = (__bf16)(a.x * d); o[1] = (__bf16)(a.y * d);
        o[2] = (__bf16)(a.z * d); o[3] = (__bf16)(a.w * d);
        o[4] = (__bf16)(b.x * d); o[5] = (__bf16)(b.y * d);
        o[6] = (__bf16)(b.z * d); o[7] = (__bf16)(b.w * d);
        ((bf16x8*)dst)[i] = o;
    }
}

// ---------------- CSR build ----------------
__global__ void deg_kernel(const int* __restrict__ dst, int* __restrict__ deg) {
    int i = blockIdx.x * blockDim.x + threadIdx.x;
    if (i < N_EDGES) atomicAdd(&deg[dst[i]], 1);
}

// per-block sums of (deg+1); also emits dinv (fused)
__global__ __launch_bounds__(256) void scan_bsum(const int* __restrict__ deg,
                                                 int* __restrict__ bsum,
                                                 float* __restrict__ dinv) {
    __shared__ int lds[256];
    int i = blockIdx.x * 256 + threadIdx.x;
    int dv = 0;
    if (i < N_NODES) {
        dv = deg[i] + 1;
        dinv[i] = rsqrtf((float)dv);
    }
    lds[threadIdx.x] = dv;
    __syncthreads();
    #pragma unroll
    for (int off = 128; off > 0; off >>= 1) {
        if (threadIdx.x < off) lds[threadIdx.x] += lds[threadIdx.x + off];
        __syncthreads();
    }
    if (threadIdx.x == 0) bsum[blockIdx.x] = lds[0];
}

__global__ __launch_bounds__(256) void scan_boffs(const int* __restrict__ bsum,
                                                  int* __restrict__ boffs) {
    __shared__ int lds[256];
    const int t = threadIdx.x;
    lds[t] = (t < SCAN_NB) ? bsum[t] : 0;
    __syncthreads();
    #pragma unroll
    for (int off = 1; off < 256; off <<= 1) {
        int add = (t >= off) ? lds[t - off] : 0;
        __syncthreads();
        lds[t] += add;
        __syncthreads();
    }
    boffs[t] = (t == 0) ? 0 : lds[t - 1];   // exclusive
}

__global__ __launch_bounds__(256) void scan_write(const int* __restrict__ deg,
                                                  const int* __restrict__ boffs,
                                                  int* __restrict__ rp) {
    __shared__ int lds[256];
    const int t = threadIdx.x;
    int i = blockIdx.x * 256 + t;
    int v = (i < N_NODES) ? deg[i] + 1 : 0;
    lds[t] = v;
    __syncthreads();
    #pragma unroll
    for (int off = 1; off < 256; off <<= 1) {
        int add = (t >= off) ? lds[t - off] : 0;
        __syncthreads();
        lds[t] += add;
        __syncthreads();
    }
    if (i < N_NODES) rp[i] = boffs[blockIdx.x] + lds[t] - v;
    if (i == N_NODES - 1) rp[N_NODES] = boffs[blockIdx.x] + lds[t];
}

// ---- bucketed CSR build: pass A scatters edges into 64-node dst-buckets ----
// bucket cursor padded to one per 64B line; regions addressed by rp[64b] (slack = self-loop slots)
__global__ void bcur_init(const int* __restrict__ rp, int* __restrict__ bcur) {
    int b = blockIdx.x * blockDim.x + threadIdx.x;
    if (b < NBUCKET) bcur[b * 16] = rp[b * 64];
}

__global__ void scatter_bucket(const int* __restrict__ ei, int* __restrict__ bcur,
                               int* __restrict__ tmp) {
    int e = blockIdx.x * blockDim.x + threadIdx.x;
    if (e >= N_EDGES) return;
    int src = ei[e], dst = ei[N_EDGES + e];
    int b = dst >> 6;
    int pos = atomicAdd(&bcur[b * 16], 1);
    tmp[pos] = src | ((dst & 63) << 17);   // src < 2^17, dstLocal in bits 17..22
}

// ---- pass B: one block per bucket; LDS cursors; line-local CSR writes ----
__global__ __launch_bounds__(256) void csr_place(const int* __restrict__ rp,
                                                 const int* __restrict__ bcur,
                                                 const int* __restrict__ tmp,
                                                 int* __restrict__ csr) {
    __shared__ int lcur[64];
    __shared__ int lrp[65];
    const int b = blockIdx.x, t = threadIdx.x;
    const int node0 = b * 64;
    if (t < 64) lcur[t] = 0;
    if (t < 65) {
        int n = node0 + t;
        lrp[t] = rp[n <= N_NODES ? n : N_NODES];
    }
    __syncthreads();
    const int estart = lrp[0];
    const int eend = bcur[b * 16];        // final cursor after pass A
    for (int e = estart + t; e < eend; e += 256) {
        int v = tmp[e];
        int src = v & 0x1FFFF;
        int dl = v >> 17;
        int slot = lrp[dl] + atomicAdd(&lcur[dl], 1);
        csr[slot] = src;
    }
    // self-loops into each node's reserved last slot
    if (t < 64) {
        int n = node0 + t;
        if (n < N_NODES) csr[lrp[t + 1] - 1] = n;
    }
}

// ---------------- SpMM: out[r] = dinv[r] * sum_e h[src[e]]  (h pre-scaled by dinv) ----
template<int C8>
__global__ __launch_bounds__(256) void spmm_b(const int* __restrict__ rp,
                                              const int* __restrict__ csr,
                                              const float* __restrict__ dinv,
                                              const __bf16* __restrict__ h,
                                              __bf16* __restrict__ outp) {
    constexpr int RPB = 256 / C8;
    const int r = blockIdx.x * RPB + threadIdx.x / C8;
    const int l = threadIdx.x % C8;
    if (r >= N_NODES) return;
    const bf16x8* __restrict__ h8 = (const bf16x8*)h;
    const int e0 = rp[r], e1 = rp[r + 1];
    float acc0[8] = {}, acc1[8] = {};
    int e = e0;
    for (; e + 8 <= e1; e += 8) {
        int p[8];
        #pragma unroll
        for (int u = 0; u < 8; ++u) p[u] = csr[e + u];
        bf16x8 v[8];
        #pragma unroll
        for (int u = 0; u < 8; ++u) v[u] = h8[(long)p[u] * C8 + l];
        #pragma unroll
        for (int u = 0; u < 8; ++u) {
            #pragma unroll
            for (int j = 0; j < 8; ++j) {
                if (u & 1) acc1[j] += (float)v[u][j];
                else       acc0[j] += (float)v[u][j];
            }
        }
    }
    for (; e + 2 <= e1; e += 2) {
        int p0 = csr[e], p1 = csr[e + 1];
        bf16x8 v0 = h8[(long)p0 * C8 + l];
        bf16x8 v1 = h8[(long)p1 * C8 + l];
        #pragma unroll
        for (int j = 0; j < 8; ++j) {
            acc0[j] += (float)v0[j];
            acc1[j] += (float)v1[j];
        }
    }
    if (e < e1) {
        int p0 = csr[e];
        bf16x8 v0 = h8[(long)p0 * C8 + l];
        #pragma unroll
        for (int j = 0; j < 8; ++j) acc0[j] += (float)v0[j];
    }
    const float d = dinv[r];
    bf16x8 ob;
    #pragma unroll
    for (int j = 0; j < 8; ++j) ob[j] = (__bf16)((acc0[j] + acc1[j]) * d);
    ((bf16x8*)outp)[(long)r * C8 + l] = ob;
}

// ---------------- bf16 MFMA GEMM, double-buffered LDS, 1 barrier / K-step ----------------
template<int K, int NC, bool FUSE_BN, bool RELU, bool SCALE>
__global__ __launch_bounds__(256) void gemm_tile(const __bf16* __restrict__ A,
                                                 const __bf16* __restrict__ W,
                                                 const float* __restrict__ ss,
                                                 const float* __restrict__ dinv,
                                                 __bf16* __restrict__ C,
                                                 int M) {
    constexpr int NW = NC / 64;
    constexpr int MW = 4 / NW;
    constexpr int BM = MW * 64;
    constexpr int NSTEP = K / 32;
    __shared__ __bf16 As[2][BM][40];

    const int tid = threadIdx.x;
    const int wave = tid >> 6, lane = tid & 63;
    const int ln15 = lane & 15, kg = lane >> 4;
    const int wm = wave / NW, wn = wave % NW;
    const int m0 = blockIdx.x * BM;
    const int srow = tid >> 2, schunk = tid & 3;

    int grow[MW];
    #pragma unroll
    for (int p = 0; p < MW; ++p) {
        int gr = m0 + p * 64 + srow;
        grow[p] = gr < M ? gr : M - 1;
    }

    f32x4 acc[4][4];
    #pragma unroll
    for (int i = 0; i < 4; ++i)
        #pragma unroll
        for (int j = 0; j < 4; ++j) acc[i][j] = (f32x4){0.f, 0.f, 0.f, 0.f};

#define LOAD_A(vv, kt_)                                                         \
    _Pragma("unroll")                                                           \
    for (int p = 0; p < MW; ++p)                                                \
        vv[p] = *(const bf16x8*)(A + (long)grow[p] * K + (kt_) + schunk * 8);

#define XFORM_A(vv, kt_)                                                        \
    if (FUSE_BN) {                                                              \
        const f32x4* ss4 = (const f32x4*)ss;                                    \
        int ci = ((kt_) + schunk * 8) >> 2;                                     \
        f32x4 sc0 = ss4[ci],            sc1 = ss4[ci + 1];                      \
        f32x4 sh0 = ss4[(K >> 2) + ci], sh1 = ss4[(K >> 2) + ci + 1];           \
        _Pragma("unroll")                                                       \
        for (int p = 0; p < MW; ++p) {                                          \
            float f[8];                                                         \
            _Pragma("unroll")                                                   \
            for (int j = 0; j < 4; ++j) {                                       \
                f[j]     = fmaf((float)vv[p][j],     sc0[j], sh0[j]);           \
                f[j + 4] = fmaf((float)vv[p][j + 4], sc1[j], sh1[j]);           \
            }                                                                   \
            if (RELU) {                                                         \
                _Pragma("unroll")                                               \
                for (int j = 0; j < 8; ++j) f[j] = f[j] > 0.f ? f[j] : SLOPE * f[j]; \
            }                                                                   \
            _Pragma("unroll")                                                   \
            for (int j = 0; j < 8; ++j) vv[p][j] = (__bf16)f[j];                \
        }                                                                       \
    }

#define WRITE_A(buf, vv)                                                        \
    _Pragma("unroll")                                                           \
    for (int p = 0; p < MW; ++p)                                                \
        *(bf16x8*)(&As[buf][p * 64 + srow][schunk * 8]) = vv[p];

    bf16x8 v0[MW], v[MW];
    LOAD_A(v0, 0)
    XFORM_A(v0, 0)
    WRITE_A(0, v0)
    if (NSTEP > 1) {
        LOAD_A(v, 32)
        XFORM_A(v, 32)
    }
    __syncthreads();

    int cur = 0;
    #pragma unroll
    for (int step = 0; step < NSTEP; ++step) {
        const int kt = step * 32;
        if (step + 1 < NSTEP) {
            WRITE_A(cur ^ 1, v)
        }
        bf16x8 vn[MW];
        if (step + 2 < NSTEP) {
            LOAD_A(vn, kt + 64)
        }
        bf16x8 b[4];
        #pragma unroll
        for (int j = 0; j < 4; ++j)
            b[j] = *(const bf16x8*)(W + (long)(wn * 64 + j * 16 + ln15) * K + kt + kg * 8);
        #pragma unroll
        for (int i = 0; i < 4; ++i) {
            bf16x8 a = *(const bf16x8*)(&As[cur][wm * 64 + i * 16 + ln15][kg * 8]);
            #pragma unroll
            for (int j = 0; j < 4; ++j)
                acc[i][j] = __builtin_amdgcn_mfma_f32_16x16x32_bf16(a, b[j], acc[i][j], 0, 0, 0);
        }
        if (step + 2 < NSTEP) {
            XFORM_A(vn, kt + 64)
            #pragma unroll
            for (int p = 0; p < MW; ++p) v[p] = vn[p];
        }
        __syncthreads();
        cur ^= 1;
    }
#undef LOAD_A
#undef XFORM_A
#undef WRITE_A

    #pragma unroll
    for (int i = 0; i < 4; ++i) {
        #pragma unroll
        for (int q = 0; q < 4; ++q) {
            int r = m0 + wm * 64 + i * 16 + kg * 4 + q;
            if (r < M) {
                float d = SCALE ? dinv[r] : 1.0f;
                #pragma unroll
                for (int j = 0; j < 4; ++j)
                    C[(long)r * NC + wn * 64 + j * 16 + ln15] = (__bf16)(acc[i][j][q] * d);
            }
        }
    }
}

// ---------------- BN stats: per-block partial sums (atomic-free, bf16 input) ----------
#define NB_STATS 128
template<int C>
__global__ __launch_bounds__(256) void bn_stats(const __bf16* __restrict__ hp,
                                                float* __restrict__ partial) {
    constexpr int LPR = C / 4;
    constexpr int RPI = 256 / LPR;
    const int chunk = threadIdx.x % LPR;
    const int rof   = threadIdx.x / LPR;
    float s[4] = {}, s2[4] = {};
    for (int r = blockIdx.x * RPI + rof; r < N_NODES; r += NB_STATS * RPI) {
        bf16x4 x = ((const bf16x4*)hp)[(long)r * LPR + chunk];
        #pragma unroll
        for (int j = 0; j < 4; ++j) {
            float v = (float)x[j];
            s[j] += v; s2[j] += v * v;
        }
    }
    __shared__ float red[256 * 8];
    #pragma unroll
    for (int j = 0; j < 4; ++j) { red[threadIdx.x * 8 + j] = s[j]; red[threadIdx.x * 8 + 4 + j] = s2[j]; }
    __syncthreads();
    if (rof == 0) {
        #pragma unroll
        for (int g = 1; g < RPI; ++g) {
            #pragma unroll
            for (int j = 0; j < 4; ++j) {
                s[j]  += red[(g * LPR + chunk) * 8 + j];
                s2[j] += red[(g * LPR + chunk) * 8 + 4 + j];
            }
        }
        #pragma unroll
        for (int j = 0; j < 4; ++j) {
            partial[blockIdx.x * 2 * C + chunk * 4 + j]     = s[j];
            partial[blockIdx.x * 2 * C + C + chunk * 4 + j] = s2[j];
        }
    }
}

// ---------------- reduce partials -> scale/shift (1024 threads, parallel groups) ----
template<int C>
__global__ __launch_bounds__(1024) void bn_reduce(const float* __restrict__ partial, int nb,
                                                  const float* __restrict__ g,
                                                  const float* __restrict__ be,
                                                  float* __restrict__ ss) {
    constexpr int G = 1024 / C;
    const int c = threadIdx.x % C;
    const int grp = threadIdx.x / C;
    float s = 0.f, q = 0.f;
    for (int b = grp; b < nb; b += G) {
        s += partial[(long)b * 2 * C + c];
        q += partial[(long)b * 2 * C + C + c];
    }
    __shared__ float reds[1024], redq[1024];
    reds[threadIdx.x] = s; redq[threadIdx.x] = q;
    __syncthreads();
    if (grp == 0) {
        #pragma unroll
        for (int gg = 1; gg < G; ++gg) { s += reds[gg * C + c]; q += redq[gg * C + c]; }
        const float invn = 1.0f / (float)N_NODES;
        float mean = s * invn;
        float var  = q * invn - mean * mean;
        float rstd = rsqrtf(var + EPSV);
        float sc = g[c] * rstd;
        ss[c] = sc;
        ss[C + c] = be[c] - mean * sc;
    }
}

// ---------------- final BN apply: bf16 in -> f32 out ----------------
template<int C>
__global__ __launch_bounds__(256) void bn_apply_b2f(const __bf16* __restrict__ in,
                                                    float* __restrict__ outp,
                                                    const float* __restrict__ ss) {
    constexpr int LPR = C / 4;
    const long total = (long)N_NODES * LPR;
    const long stride = (long)gridDim.x * blockDim.x;
    for (long idx = (long)blockIdx.x * blockDim.x + threadIdx.x; idx < total; idx += stride) {
        int chunk = (int)(idx % LPR);
        float4 sc = ((const float4*)ss)[chunk];
        float4 sh = ((const float4*)(ss + C))[chunk];
        bf16x4 x = ((const bf16x4*)in)[idx];
        float4 o;
        o.x = fmaf((float)x[0], sc.x, sh.x);
        o.y = fmaf((float)x[1], sc.y, sh.y);
        o.z = fmaf((float)x[2], sc.z, sh.z);
        o.w = fmaf((float)x[3], sc.w, sh.w);
        ((float4*)outp)[idx] = o;
    }
}

extern "C" void kernel_launch(void* const* d_in, const int* in_sizes, int n_in,
                              void* d_out, int out_size, void* d_ws, size_t ws_size,
                              hipStream_t stream) {
    const float* x   = (const float*)d_in[0];
    const int*   ei  = (const int*)  d_in[1];
    const float* W0  = (const float*)d_in[2];
    const float* g0  = (const float*)d_in[4];
    const float* be0 = (const float*)d_in[5];
    const float* W1  = (const float*)d_in[6];
    const float* g1  = (const float*)d_in[8];
    const float* be1 = (const float*)d_in[9];
    const float* W2  = (const float*)d_in[10];
    const float* g2  = (const float*)d_in[12];
    const float* be2 = (const float*)d_in[13];
    float* out = (float*)d_out;

    char* wsb = (char*)d_ws;
    auto alloc = [&](size_t bytes) { char* p = wsb; wsb += (bytes + 255) & ~255UL; return p; };
    int*    deg     = (int*)   alloc(N_NODES * 4);
    int*    rp      = (int*)   alloc((N_NODES + 4) * 4);
    float*  dinv    = (float*) alloc(N_NODES * 4);
    int*    bsum    = (int*)   alloc(256 * 4);
    int*    boffs   = (int*)   alloc(257 * 4);
    int*    bcur    = (int*)   alloc((size_t)NBUCKET * 16 * 4);
    float*  partial = (float*) alloc(NB_STATS * 2 * DH * 4);
    float*  ss      = (float*) alloc(2 * DH * 4);
    int*    csr     = (int*)   alloc((size_t)(N_EDGES + N_NODES) * 4);
    int*    tmp     = (int*)   alloc((size_t)(N_EDGES + N_NODES) * 4);
    __bf16* w0b     = (__bf16*)alloc(DH * DIN * 2);
    __bf16* w1b     = (__bf16*)alloc(DH * DH * 2);
    __bf16* w2b     = (__bf16*)alloc(DOUT * DH * 2);
    __bf16* xb      = (__bf16*)alloc((size_t)N_NODES * DIN * 2);
    __bf16* bf0     = (__bf16*)alloc((size_t)N_NODES * DH * 2);
    __bf16* bf1     = (__bf16*)alloc((size_t)N_NODES * DH * 2);

    hipMemsetAsync(deg, 0, N_NODES * 4, stream);

    // ---- merged weight casts ----
    cast3_kernel<<<(DH * DIN / 4 + DH * DH / 4 + DOUT * DH / 4 + 255) / 256, 256, 0, stream>>>(
        W0, W1, W2, w0b, w1b, w2b);

    // ---- CSR build: deg -> scans -> bucketed two-phase scatter ----
    deg_kernel<<<(N_EDGES + 255) / 256, 256, 0, stream>>>(ei + N_EDGES, deg);
    scan_bsum<<<SCAN_NB, 256, 0, stream>>>(deg, bsum, dinv);
    scan_boffs<<<1, 256, 0, stream>>>(bsum, boffs);
    scan_write<<<SCAN_NB, 256, 0, stream>>>(deg, boffs, rp);
    bcur_init<<<(NBUCKET + 255) / 256, 256, 0, stream>>>(rp, bcur);
    scatter_bucket<<<(N_EDGES + 255) / 256, 256, 0, stream>>>(ei, bcur, tmp);
    csr_place<<<NBUCKET, 256, 0, stream>>>(rp, bcur, tmp, csr);

    // ---- x -> bf16 pre-scaled by dinv ----
    cast_scale_kernel<<<(N_NODES * (DIN / 8) + 255) / 256, 256, 0, stream>>>(x, dinv, xb);

    // ---- layer 0: aggregate xb (C=128) -> gemm0 -> stats ----
    spmm_b<DIN / 8><<<(N_NODES * (DIN / 8) + 255) / 256, 256, 0, stream>>>(
        rp, csr, dinv, xb, bf0);
    gemm_tile<DIN, DH, false, false, false><<<(N_NODES + 63) / 64, 256, 0, stream>>>(
        bf0, w0b, nullptr, nullptr, bf1, N_NODES);
    bn_stats<DH><<<NB_STATS, 256, 0, stream>>>(bf1, partial);
    bn_reduce<DH><<<1, 1024, 0, stream>>>(partial, NB_STATS, g0, be0, ss);

    // ---- layer 1: gemm (fused BN0+leaky, dinv-scaled) -> aggregate -> stats ----
    gemm_tile<DH, DH, true, true, true><<<(N_NODES + 63) / 64, 256, 0, stream>>>(
        bf1, w1b, ss, dinv, bf0, N_NODES);
    spmm_b<DH / 8><<<(N_NODES * (DH / 8) + 255) / 256, 256, 0, stream>>>(
        rp, csr, dinv, bf0, bf1);
    bn_stats<DH><<<NB_STATS, 256, 0, stream>>>(bf1, partial);
    bn_reduce<DH><<<1, 1024, 0, stream>>>(partial, NB_STATS, g1, be1, ss);

    // ---- layer 2: gemm (fused BN1+leaky, dinv-scaled) -> aggregate bf16 -> stats -> BN ----
    gemm_tile<DH, DOUT, true, true, true><<<(N_NODES + 127) / 128, 256, 0, stream>>>(
        bf1, w2b, ss, dinv, bf0, N_NODES);
    spmm_b<DOUT / 8><<<(N_NODES * (DOUT / 8) + 255) / 256, 256, 0, stream>>>(
        rp, csr, dinv, bf0, bf1);
    bn_stats<DOUT><<<NB_STATS, 256, 0, stream>>>(bf1, partial);
    bn_reduce<DOUT><<<1, 1024, 0, stream>>>(partial, NB_STATS, g2, be2, ss);
    bn_apply_b2f<DOUT><<<2048, 256, 0, stream>>>(bf1, out, ss);
}